// Round 1
// baseline (120.311 us; speedup 1.0000x reference)
//
#include <hip/hip_runtime.h>

#define H 1536
#define HK 8
#define HV 16
#define DK 64
#define DV 64
#define KEY_DIM 512
#define VALUE_DIM 1024
#define CONV_DIM 2048
#define NROWS1 (CONV_DIM + VALUE_DIM + HV + HV)   // 3104
#define NBLK 256                                   // == CU count; all blocks co-resident

// Monotonic ticket barrier counter. Lives in module .bss (zero at load), NOT in the
// poisoned workspace. Never reset: each barrier episode consumes NBLK tickets, so it
// is safe across warmups, graph replays, and rocprof counter-replay passes.
__device__ unsigned g_ticket = 0;

__device__ __forceinline__ float wave_reduce_sum(float v) {
#pragma unroll
    for (int off = 32; off > 0; off >>= 1) v += __shfl_xor(v, off, 64);
    return v;
}

__device__ __forceinline__ float dot4(float4 a, float4 b) {
    return a.x * b.x + a.y * b.y + a.z * b.z + a.w * b.w;
}

// Device-scope grid barrier. Soundness: a block cannot take its episode-k+1 ticket
// before passing episode k, and passing episode k requires all NBLK episode-k tickets
// to exist; by induction tickets [k*NBLK,(k+1)*NBLK) are exactly the k-th arrivals.
// ACQ_REL/ACQUIRE at AGENT scope emit the L2 writeback / L1+L2 invalidate needed for
// cross-XCD visibility of the normal stores/loads around the barrier.
__device__ __forceinline__ void grid_barrier() {
    __syncthreads();
    if (threadIdx.x == 0) {
        unsigned t = __hip_atomic_fetch_add(&g_ticket, 1u, __ATOMIC_ACQ_REL,
                                            __HIP_MEMORY_SCOPE_AGENT);
        unsigned target = (t / NBLK + 1u) * NBLK;
        while (__hip_atomic_load(&g_ticket, __ATOMIC_ACQUIRE,
                                 __HIP_MEMORY_SCOPE_AGENT) < target)
            __builtin_amdgcn_s_sleep(2);
    }
    __syncthreads();
}

// One persistent kernel:
//   prefetch (state->LDS for decode blocks, W_out rows->registers for everyone)
//   phase 1: fused GEMV for W_qkv|W_z|W_a|W_b (3104 rows over 1024 waves)
//   barrier
//   phase 2: conv+silu+l2norm+delta-rule+gated RMSNorm (blocks 0..15, one head each)
//   barrier
//   phase 3: y = W_out @ og using the registers preloaded before phase 1
__global__ __launch_bounds__(256) void fused_decode(
        const float* __restrict__ x,
        const float* __restrict__ Wqkv, const float* __restrict__ Wz,
        const float* __restrict__ Wa,   const float* __restrict__ Wb,
        const float* __restrict__ Wout,
        const float* __restrict__ conv_w, const float* __restrict__ conv_cache,
        const float* __restrict__ A_log, const float* __restrict__ dt_bias,
        const float* __restrict__ norm_w,
        const float* __restrict__ state,
        float* __restrict__ ws,                 // [3104]: qkv | z | a | b
        float* __restrict__ og,                 // [1024]: gated output
        float* __restrict__ y) {                // [1536]
    const int tid  = threadIdx.x;
    const int lane = tid & 63;
    const int wv   = tid >> 6;
    const int blk  = blockIdx.x;
    const int wg   = blk * 4 + wv;              // global wave id, 0..1023

    __shared__ float s_state[DK * DV];          // 16 KB, used by decode blocks only
    __shared__ float q_s[64], k_s[64], v_s[64];
    __shared__ float red_r[256], red_o[256];
    __shared__ float scal[3];                   // decay, beta, k·q

    // ---- Prefetch A: state -> LDS for decode blocks (overlaps phase-1 HBM traffic)
    if (blk < HV) {
        const float4* st4 = (const float4*)(state + (size_t)blk * DK * DV);
        float4* ss4 = (float4*)s_state;
#pragma unroll
        for (int j = 0; j < 4; ++j) ss4[tid + 256 * j] = st4[tid + 256 * j];
    }

    // ---- Prefetch B: W_out rows into registers (consumed in phase 3)
    float4 wo0[4], wo1[4] = {};
    {
        const float4* w4 = (const float4*)(Wout + (size_t)wg * VALUE_DIM);
#pragma unroll
        for (int j = 0; j < 4; ++j) wo0[j] = w4[lane + 64 * j];
    }
    if (wg < 512) {
        const float4* w4 = (const float4*)(Wout + (size_t)(1024 + wg) * VALUE_DIM);
#pragma unroll
        for (int j = 0; j < 4; ++j) wo1[j] = w4[lane + 64 * j];
    }

    // ---- Phase 1: input GEMV. 3 contiguous rows per wave covers 0..3071; the 32
    // W_a/W_b rows are spread one-per-block over blocks 208..239 (wave 0) so no CU
    // carries more than one extra row (tail balance).
    auto rowptr = [&](int row) -> const float* {
        if (row < CONV_DIM)                  return Wqkv + (size_t)row * H;
        if (row < CONV_DIM + VALUE_DIM)      return Wz + (size_t)(row - CONV_DIM) * H;
        if (row < CONV_DIM + VALUE_DIM + HV) return Wa + (size_t)(row - CONV_DIM - VALUE_DIM) * H;
        return Wb + (size_t)(row - CONV_DIM - VALUE_DIM - HV) * H;
    };
    const int r0 = wg * 3;
    const float4* wA = (const float4*)rowptr(r0);
    const float4* wB = (const float4*)rowptr(r0 + 1);
    const float4* wC = (const float4*)rowptr(r0 + 2);
    const bool extra = (wv == 0) && (blk >= 208) && (blk < 240);
    const int erow = 3072 + blk - 208;
    const float4* wD = (const float4*)rowptr(extra ? erow : r0);
    const float4* x4 = (const float4*)x;

    float a0 = 0.f, a1 = 0.f, a2 = 0.f, a3 = 0.f;
#pragma unroll
    for (int j = 0; j < 6; ++j) {               // 1536/4/64 = 6
        const int idx = lane + 64 * j;
        const float4 xb = x4[idx];
        a0 += dot4(wA[idx], xb);
        a1 += dot4(wB[idx], xb);
        a2 += dot4(wC[idx], xb);
        if (extra) a3 += dot4(wD[idx], xb);
    }
    a0 = wave_reduce_sum(a0);
    a1 = wave_reduce_sum(a1);
    a2 = wave_reduce_sum(a2);
    if (lane == 0) { ws[r0] = a0; ws[r0 + 1] = a1; ws[r0 + 2] = a2; }
    if (extra) {
        a3 = wave_reduce_sum(a3);
        if (lane == 0) ws[erow] = a3;
    }

    grid_barrier();

    // ---- Phase 2: decode core, blocks 0..15 (one head each), state from LDS.
    if (blk < HV) {
        const int h = blk;
        const int grp = wv;
        if (grp < 3) {
            int i;
            if (grp == 0)      i = (h >> 1) * 64 + lane;                // q row (kv-group repeat)
            else if (grp == 1) i = KEY_DIM + (h >> 1) * 64 + lane;      // k row
            else               i = 2 * KEY_DIM + h * 64 + lane;         // v row
            float raw = conv_cache[i * 3 + 0] * conv_w[i * 4 + 0]
                      + conv_cache[i * 3 + 1] * conv_w[i * 4 + 1]
                      + conv_cache[i * 3 + 2] * conv_w[i * 4 + 2]
                      + ws[i]                 * conv_w[i * 4 + 3];
            float c = raw / (1.f + expf(-raw));       // silu
            if (grp == 2) {
                v_s[lane] = c;
            } else {
                float ss  = wave_reduce_sum(c * c);
                float inv = rsqrtf(ss + 1e-12f);      // l2_normalize
                if (grp == 0) q_s[lane] = c * inv * 0.125f;  // * Dk^-0.5
                else          k_s[lane] = c * inv;
            }
        } else if (lane == 0) {
            float aa = ws[CONV_DIM + VALUE_DIM + h] + dt_bias[h];
            float sp = (aa > 20.f) ? aa : log1pf(expf(aa));  // softplus
            scal[0] = expf(-expf(A_log[h]) * sp);            // decay
            float braw = ws[CONV_DIM + VALUE_DIM + HV + h];
            scal[1] = 1.f / (1.f + expf(-braw));             // beta
        }
        __syncthreads();

        float pr = 0.f, po = 0.f;
        const int k0 = grp * 16;
#pragma unroll
        for (int kk = 0; kk < 16; ++kk) {
            float s = s_state[(k0 + kk) * 64 + lane];        // 2-way LDS alias: free
            pr += s * k_s[k0 + kk];
            po += s * q_s[k0 + kk];
        }
        red_r[tid] = pr;
        red_o[tid] = po;
        if (grp == 0) {
            float t = wave_reduce_sum(k_s[lane] * q_s[lane]);
            if (lane == 0) scal[2] = t;
        }
        __syncthreads();

        if (tid < 64) {
            const float decay = scal[0], beta = scal[1], kq = scal[2];
            float r = (red_r[tid] + red_r[64 + tid] + red_r[128 + tid] + red_r[192 + tid]) * decay;
            float o = (red_o[tid] + red_o[64 + tid] + red_o[128 + tid] + red_o[192 + tid]) * decay;
            float delta = (v_s[tid] - r) * beta;
            float outv  = o + delta * kq;                    // new_state^T q, unmaterialized
            float ss  = wave_reduce_sum(outv * outv);
            float inv = rsqrtf(ss * (1.f / 64.f) + 1e-6f);
            float zz  = ws[CONV_DIM + h * 64 + tid];
            float gate = zz / (1.f + expf(-zz));             // silu(z)
            og[h * 64 + tid] = norm_w[tid] * outv * inv * gate;
        }
    }

    grid_barrier();

    // ---- Phase 3: y = W_out @ og with W_out already in registers; og is L2/L3-hot.
    const float4* og4 = (const float4*)og;
    const float4 g0 = og4[lane];
    const float4 g1 = og4[lane + 64];
    const float4 g2 = og4[lane + 128];
    const float4 g3 = og4[lane + 192];
    float acc = dot4(wo0[0], g0) + dot4(wo0[1], g1) + dot4(wo0[2], g2) + dot4(wo0[3], g3);
    acc = wave_reduce_sum(acc);
    if (lane == 0) y[wg] = acc;
    if (wg < 512) {
        float acc2 = dot4(wo1[0], g0) + dot4(wo1[1], g1) + dot4(wo1[2], g2) + dot4(wo1[3], g3);
        acc2 = wave_reduce_sum(acc2);
        if (lane == 0) y[1024 + wg] = acc2;
    }
}

extern "C" void kernel_launch(void* const* d_in, const int* in_sizes, int n_in,
                              void* d_out, int out_size, void* d_ws, size_t ws_size,
                              hipStream_t stream) {
    const float* x     = (const float*)d_in[0];
    const float* Wqkv  = (const float*)d_in[1];
    const float* Wz    = (const float*)d_in[2];
    const float* Wa    = (const float*)d_in[3];
    const float* Wb    = (const float*)d_in[4];
    const float* Wout  = (const float*)d_in[5];
    const float* convw = (const float*)d_in[6];
    const float* Alog  = (const float*)d_in[7];
    const float* dtb   = (const float*)d_in[8];
    const float* normw = (const float*)d_in[9];
    const float* state = (const float*)d_in[10];
    const float* cch   = (const float*)d_in[11];

    float* ws = (float*)d_ws;              // [0,3104): qkv|z|a|b
    float* og = ws + NROWS1;               // [3104,4128): gated out (3104*4 % 16 == 0)
    float* y  = (float*)d_out;

    fused_decode<<<NBLK, 256, 0, stream>>>(x, Wqkv, Wz, Wa, Wb, Wout, convw, cch,
                                           Alog, dtb, normw, state, ws, og, y);
}